// Round 15
// baseline (2638.990 us; speedup 1.0000x reference)
//
#include <hip/hip_runtime.h>
#include <cstddef>

// ---------------------------------------------------------------------------
// EGNN layer, fp32. R15 = R14 with edge LDS cut for occupancy:
//   - edge: single sW[64][64] weight buffer, restaged per phase (W2^T during
//     phase-0, P1^T after m-writeback; existing barriers cover the hazards).
//     LDS 53->36 KB => 4 blocks/CU (was 3). Restage = 32KB/tile from hot
//     L1/L2 (~45us aggregate). Same values, bit-identical outputs.
//   sort chain / node_pre / gru: R14-identical (validated, 1859us total).
// ---------------------------------------------------------------------------

__device__ __forceinline__ float silu_f(float v) {
    return v * __builtin_amdgcn_rcpf(1.0f + __expf(-v));
}
__device__ __forceinline__ float sigmoid_fast(float v) {
    return __builtin_amdgcn_rcpf(1.0f + __expf(-v));
}
__device__ __forceinline__ float tanh_fast(float v) {
    return 2.0f * __builtin_amdgcn_rcpf(1.0f + __expf(-2.0f * v)) - 1.0f;
}

// ---------------- sort: histogram / scan / scatter ---------------------------
__global__ __launch_bounds__(256) void hist_kernel(
    const int* __restrict__ src, int* __restrict__ hist, int E)
{
    int i = blockIdx.x * 256 + threadIdx.x;
    int stride = gridDim.x * 256;
    for (; i < E; i += stride) atomicAdd(&hist[src[i]], 1);
}

#define SCAN_CHUNK 2048

__global__ __launch_bounds__(256) void scanA_kernel(
    const int* __restrict__ hist, int* __restrict__ blksum, int N)
{
    __shared__ int sred[256];
    int b = blockIdx.x, tx = threadIdx.x;
    int base = b * SCAN_CHUNK + tx * 8;
    int s = 0;
    #pragma unroll
    for (int i = 0; i < 8; ++i) { int idx = base + i; if (idx < N) s += hist[idx]; }
    sred[tx] = s; __syncthreads();
    for (int off = 128; off > 0; off >>= 1) {
        if (tx < off) sred[tx] += sred[tx + off];
        __syncthreads();
    }
    if (tx == 0) blksum[b] = sred[0];
}

__global__ void scanB_kernel(int* __restrict__ blksum, int B)
{
    if (blockIdx.x == 0 && threadIdx.x == 0) {
        int acc = 0;
        for (int i = 0; i < B; ++i) { int v = blksum[i]; blksum[i] = acc; acc += v; }
    }
}

__global__ __launch_bounds__(256) void scanC_kernel(
    const int* __restrict__ hist, const int* __restrict__ blksum,
    int* __restrict__ cursor, int N)
{
    __shared__ int sscan[256];
    int b = blockIdx.x, tx = threadIdx.x;
    int base = b * SCAN_CHUNK + tx * 8;
    int s = 0;
    #pragma unroll
    for (int i = 0; i < 8; ++i) { int idx = base + i; if (idx < N) s += hist[idx]; }
    int mysum = s;
    sscan[tx] = s; __syncthreads();
    for (int off = 1; off < 256; off <<= 1) {
        int v = (tx >= off) ? sscan[tx - off] : 0;
        __syncthreads();
        sscan[tx] += v;
        __syncthreads();
    }
    int run = blksum[b] + sscan[tx] - mysum;
    #pragma unroll
    for (int i = 0; i < 8; ++i) {
        int idx = base + i;
        if (idx < N) { cursor[idx] = run; run += hist[idx]; }
    }
}

__global__ __launch_bounds__(256) void scatter_kernel(
    const int* __restrict__ src, int* __restrict__ cursor,
    int* __restrict__ order, int E)
{
    int i = blockIdx.x * 256 + threadIdx.x;
    int stride = gridDim.x * 256;
    for (; i < E; i += stride) {
        int p = atomicAdd(&cursor[src[i]], 1);
        order[p] = i;
    }
}

// ---------------- K1: per-node precompute (LDS-staged W1^T, float4) ----------
__global__ __launch_bounds__(256) void node_pre_kernel(
    const float* __restrict__ h, const float* __restrict__ W1,
    const float* __restrict__ b1,
    float* __restrict__ H1a, float* __restrict__ H1b, int N)
{
    __shared__ float sh[16][68];
    __shared__ float sWT[64][132];
    __shared__ float sb1[64];
    int n0 = blockIdx.x * 16;
    int tx = threadIdx.x;
    for (int i = tx; i < 64 * 128; i += 256) {
        int o = i & 127, k = i >> 7;
        sWT[k][o] = (o < 64) ? W1[o * 129 + k] : W1[(o - 64) * 129 + 64 + k];
    }
    if (tx < 64) sb1[tx] = b1[tx];
    for (int i = tx; i < 16 * 64; i += 256) {
        int ln = i >> 6, k = i & 63;
        int n = n0 + ln;
        sh[ln][k] = (n < N) ? h[(size_t)n * 64 + k] : 0.0f;
    }
    __syncthreads();
    int ln = tx >> 4;
    int lane = tx & 15;
    int n = n0 + ln;
    if (n >= N) return;
    int o0 = lane * 8;
    float acc[8];
    #pragma unroll
    for (int q = 0; q < 8; ++q) acc[q] = (o0 < 64) ? sb1[o0 + q] : 0.0f;
    #pragma unroll 8
    for (int k = 0; k < 64; ++k) {
        float a = sh[ln][k];
        float4 w0 = *(const float4*)&sWT[k][o0];
        float4 w1 = *(const float4*)&sWT[k][o0 + 4];
        acc[0] += a * w0.x; acc[1] += a * w0.y; acc[2] += a * w0.z; acc[3] += a * w0.w;
        acc[4] += a * w1.x; acc[5] += a * w1.y; acc[6] += a * w1.z; acc[7] += a * w1.w;
    }
    if (o0 < 64) {
        *(float4*)(H1a + (size_t)n * 64 + o0)     = make_float4(acc[0], acc[1], acc[2], acc[3]);
        *(float4*)(H1a + (size_t)n * 64 + o0 + 4) = make_float4(acc[4], acc[5], acc[6], acc[7]);
    } else {
        int ob = o0 - 64;
        *(float4*)(H1b + (size_t)n * 64 + ob)     = make_float4(acc[0], acc[1], acc[2], acc[3]);
        *(float4*)(H1b + (size_t)n * 64 + ob + 4) = make_float4(acc[4], acc[5], acc[6], acc[7]);
    }
}

// ---------------- K2: edge pipeline on sorted order --------------------------
__device__ __forceinline__ void tile_gemm(
    const float (*__restrict__ Ain)[68],   // [k][e]
    const float (*__restrict__ WT)[64],    // [k][f]
    int te, int tf, float (&acc)[4][4])
{
    #pragma unroll
    for (int q = 0; q < 4; ++q)
        acc[q][0] = acc[q][1] = acc[q][2] = acc[q][3] = 0.0f;
    #pragma unroll
    for (int k = 0; k < 64; k += 4) {
        float4 av[4], wv[4];
        #pragma unroll
        for (int kk = 0; kk < 4; ++kk) av[kk] = *(const float4*)&Ain[k + kk][4 * te];
        #pragma unroll
        for (int kk = 0; kk < 4; ++kk) wv[kk] = *(const float4*)&WT[k + kk][4 * tf];
        #pragma unroll
        for (int kk = 0; kk < 4; ++kk) {
            float a0 = av[kk].x, a1 = av[kk].y, a2 = av[kk].z, a3 = av[kk].w;
            float w0 = wv[kk].x, w1 = wv[kk].y, w2 = wv[kk].z, w3 = wv[kk].w;
            acc[0][0] += a0 * w0; acc[0][1] += a0 * w1; acc[0][2] += a0 * w2; acc[0][3] += a0 * w3;
            acc[1][0] += a1 * w0; acc[1][1] += a1 * w1; acc[1][2] += a1 * w2; acc[1][3] += a1 * w3;
            acc[2][0] += a2 * w0; acc[2][1] += a2 * w1; acc[2][2] += a2 * w2; acc[2][3] += a2 * w3;
            acc[3][0] += a3 * w0; acc[3][1] += a3 * w1; acc[3][2] += a3 * w2; acc[3][3] += a3 * w3;
        }
    }
}

__global__ __launch_bounds__(256) void edge_kernel(
    const float* __restrict__ H1a, const float* __restrict__ H1b,
    const float* __restrict__ x,
    const float* __restrict__ r_ij, const float* __restrict__ e_ij,
    const int* __restrict__ src, const int* __restrict__ dst,
    const int* __restrict__ order,
    const float* __restrict__ W1, const float* __restrict__ W2,
    const float* __restrict__ b2, const float* __restrict__ P1,
    const float* __restrict__ pb1, const float* __restrict__ P2,
    const float* __restrict__ pb2,
    float* __restrict__ m_sum, float* __restrict__ x_sum, int E)
{
    __shared__ float sW[64][64];     // [k][f]: W2^T for GEMM1, P1^T for GEMM2
    __shared__ float sA[64][68];     // [k][e] as t1, then [f][e] as m (in place)
    __shared__ float sXc[3][64];
    __shared__ int   sSrc[64];
    __shared__ int   sEid[64];
    __shared__ int   sRunStart[65];
    __shared__ int   sNRuns, sValid;
    __shared__ float sP2[64], sb2v[64], spb1[64], sW1c[64];
    __shared__ float spb2s;

    int tx = threadIdx.x;
    if (tx < 64) {
        sP2[tx]  = P2[tx];
        sb2v[tx] = b2[tx];
        spb1[tx] = pb1[tx];
        sW1c[tx] = W1[tx * 129 + 128];
    }
    if (tx == 0) spb2s = pb2[0];
    __syncthreads();

    int tf = tx & 15, te = tx >> 4;
    int ntile = (E + 63) >> 6;
    for (int t = blockIdx.x; t < ntile; t += gridDim.x) {
        int e0 = t << 6;

        // ---- stage W2^T (sW free after previous tile's B4) + phase 0 gather
        for (int i = tx; i < 64 * 64; i += 256) {
            int f = i >> 6, k = i & 63;
            sW[k][f] = W2[f * 64 + k];
        }
        {
            int le = tx >> 2, j = tx & 3;
            int ep = e0 + le;
            bool ok = ep < E;
            int eid = ok ? order[ep] : 0;
            int s = src[eid], d = dst[eid];
            float r = r_ij[eid];
            if (j == 0) { sSrc[le] = ok ? s : -1; sEid[le] = eid; }
            const float* pa = H1a + (size_t)s * 64 + j * 16;
            const float* pb = H1b + (size_t)d * 64 + j * 16;
            #pragma unroll
            for (int q = 0; q < 4; ++q) {
                float4 va = *(const float4*)(pa + 4 * q);
                float4 vb = *(const float4*)(pb + 4 * q);
                int f = j * 16 + 4 * q;
                sA[f + 0][le] = silu_f(va.x + vb.x + r * sW1c[f + 0]);
                sA[f + 1][le] = silu_f(va.y + vb.y + r * sW1c[f + 1]);
                sA[f + 2][le] = silu_f(va.z + vb.z + r * sW1c[f + 2]);
                sA[f + 3][le] = silu_f(va.w + vb.w + r * sW1c[f + 3]);
            }
        }
        __syncthreads();                        // B1: sA(t1), sW(W2T), sSrc ready

        // ---- run detection (wave 0; all ballots with full wave active) ----
        if (tx < 64) {
            int le = tx;
            int sv = sSrc[le];
            bool valid = sv >= 0;
            bool flag = valid && (le == 0 || sSrc[le - 1] != sv);
            unsigned long long vm = __ballot(valid);
            unsigned long long fm = __ballot(flag);
            if (flag) {
                int idx = __popcll(fm & ((1ull << le) - 1ull));
                sRunStart[idx] = le;
            }
            if (le == 0) {
                sNRuns = __popcll(fm);
                sValid = __popcll(vm);
            }
        }

        // ---- GEMM1: m = silu(t1@W2^T + b2), held in registers
        float m4v[4][4];
        {
            float acc[4][4];
            tile_gemm(sA, sW, te, tf, acc);
            #pragma unroll
            for (int c = 0; c < 4; ++c) {
                float b = sb2v[4 * tf + c];
                m4v[0][c] = silu_f(acc[0][c] + b);
                m4v[1][c] = silu_f(acc[1][c] + b);
                m4v[2][c] = silu_f(acc[2][c] + b);
                m4v[3][c] = silu_f(acc[3][c] + b);
            }
        }
        __syncthreads();                        // B2: reads of sA(t1), sW(W2T) done

        // ---- write m into sA in place + stage P1^T into sW
        #pragma unroll
        for (int c = 0; c < 4; ++c) {
            float4 m4 = make_float4(m4v[0][c], m4v[1][c], m4v[2][c], m4v[3][c]);
            *(float4*)&sA[4 * tf + c][4 * te] = m4;
        }
        for (int i = tx; i < 64 * 64; i += 256) {
            int f = i >> 6, k = i & 63;
            sW[k][f] = P1[f * 64 + k];
        }
        __syncthreads();                        // B3: sA(m), sW(P1T) visible

        // ---- GEMM2: p = silu(m@P1^T+pb1); w = p.P2 + pb2 -> sXc = e_ij*w
        {
            float acc[4][4];
            tile_gemm(sA, sW, te, tf, acc);
            float w0 = 0.0f, w1 = 0.0f, w2 = 0.0f, w3 = 0.0f;
            #pragma unroll
            for (int c = 0; c < 4; ++c) {
                float p2 = sP2[4 * tf + c];
                float bb = spb1[4 * tf + c];
                w0 += silu_f(acc[0][c] + bb) * p2;
                w1 += silu_f(acc[1][c] + bb) * p2;
                w2 += silu_f(acc[2][c] + bb) * p2;
                w3 += silu_f(acc[3][c] + bb) * p2;
            }
            #pragma unroll
            for (int mask = 1; mask < 16; mask <<= 1) {
                w0 += __shfl_xor(w0, mask);
                w1 += __shfl_xor(w1, mask);
                w2 += __shfl_xor(w2, mask);
                w3 += __shfl_xor(w3, mask);
            }
            if (tf < 4) {
                int eloc = 4 * te + tf;
                int ep = e0 + eloc;
                if (ep < E) {
                    float w = ((tf == 0) ? w0 : (tf == 1) ? w1 : (tf == 2) ? w2 : w3) + spb2s;
                    int eid = sEid[eloc];
                    sXc[0][eloc] = e_ij[(size_t)eid * 3 + 0] * w;
                    sXc[1][eloc] = e_ij[(size_t)eid * 3 + 1] * w;
                    sXc[2][eloc] = e_ij[(size_t)eid * 3 + 2] * w;
                }
            }
        }

        // ---- m segmented reduction (reads sA(m)), bank-conflict-free layout
        {
            int l15 = tx & 15;
            int eslot = (tx >> 4) & 3;
            int sg = tx >> 6;
            int f = sg * 16 + l15;
            int nr = sNRuns, vc = sValid;
            for (int ridx = 0; ridx < nr; ++ridx) {
                int st = sRunStart[ridx];
                int en = (ridx + 1 < nr) ? sRunStart[ridx + 1] : vc;
                float s = 0.0f;
                for (int e = st + eslot; e < en; e += 4) s += sA[f][e];
                s += __shfl_xor(s, 16);
                s += __shfl_xor(s, 32);
                if (eslot == 0) {
                    int node = sSrc[st];
                    atomicAdd(&m_sum[(size_t)node * 64 + f], s);
                }
            }
        }
        __syncthreads();                        // B4: sXc ready; sW/sA reads done

        // ---- x segmented reduction: one thread per run
        if (tx < sNRuns) {
            int nr = sNRuns;
            int st = sRunStart[tx];
            int en = (tx + 1 < nr) ? sRunStart[tx + 1] : sValid;
            int node = sSrc[st];
            float s0 = 0.0f, s1 = 0.0f, s2 = 0.0f;
            for (int e = st; e < en; ++e) {
                s0 += sXc[0][e]; s1 += sXc[1][e]; s2 += sXc[2][e];
            }
            float len = (float)(en - st);
            atomicAdd(&x_sum[(size_t)node * 3 + 0], s0 + len * x[(size_t)node * 3 + 0]);
            atomicAdd(&x_sum[(size_t)node * 3 + 1], s1 + len * x[(size_t)node * 3 + 1]);
            atomicAdd(&x_sum[(size_t)node * 3 + 2], s2 + len * x[(size_t)node * 3 + 2]);
        }
        __syncthreads();                        // Bend: before next tile's writes
    }
}

// ---------------- K3: GRU + x finalize (R14, validated) ----------------------
__global__ __launch_bounds__(256) void gru_kernel(
    const float* __restrict__ h, const float* __restrict__ x,
    const float* __restrict__ m_sum, const float* __restrict__ x_sum,
    const int* __restrict__ cnt,
    const float* __restrict__ W_ih, const float* __restrict__ W_hh,
    const float* __restrict__ b_ih, const float* __restrict__ b_hh,
    float* __restrict__ out_xmod, float* __restrict__ out_xdiff,
    float* __restrict__ out_h, int N)
{
    __shared__ float sWih[192][68];
    __shared__ float sWhh[192][68];
    __shared__ float smi[16][68];
    __shared__ float shv[16][68];
    __shared__ float sgi[16][196];
    __shared__ float sgh[16][196];

    int tx = threadIdx.x;
    for (int i = tx; i < 192 * 64; i += 256) {
        int f = i >> 6, k = i & 63;
        sWih[f][k] = W_ih[i];
        sWhh[f][k] = W_hh[i];
    }
    __syncthreads();

    int ntile = (N + 15) >> 4;
    for (int t = blockIdx.x; t < ntile; t += gridDim.x) {
        int n0 = t << 4;

        for (int i = tx; i < 16 * 64; i += 256) {
            int ln = i >> 6, f = i & 63;
            int n = n0 + ln;
            if (n < N) {
                float c = (float)max(cnt[n], 1);
                smi[ln][f] = m_sum[(size_t)n * 64 + f] / c;
                shv[ln][f] = h[(size_t)n * 64 + f];
            } else { smi[ln][f] = 0.0f; shv[ln][f] = 0.0f; }
        }
        __syncthreads();
        {
            int ln = tx >> 4, lane = tx & 15;
            int n = n0 + ln;
            if (n < N) {
                float ai[12], ah[12];
                #pragma unroll
                for (int oq = 0; oq < 12; ++oq) {
                    int f = oq * 16 + lane;
                    ai[oq] = b_ih[f];
                    ah[oq] = b_hh[f];
                }
                #pragma unroll 4
                for (int k4 = 0; k4 < 16; ++k4) {
                    float4 mi4 = *(const float4*)&smi[ln][4 * k4];
                    float4 hv4 = *(const float4*)&shv[ln][4 * k4];
                    #pragma unroll
                    for (int oq = 0; oq < 12; ++oq) {
                        int f = oq * 16 + lane;
                        float4 wiv = *(const float4*)&sWih[f][4 * k4];
                        float4 whv = *(const float4*)&sWhh[f][4 * k4];
                        ai[oq] += mi4.x * wiv.x + mi4.y * wiv.y + mi4.z * wiv.z + mi4.w * wiv.w;
                        ah[oq] += hv4.x * whv.x + hv4.y * whv.y + hv4.z * whv.z + hv4.w * whv.w;
                    }
                }
                #pragma unroll
                for (int oq = 0; oq < 12; ++oq) {
                    int f = oq * 16 + lane;
                    sgi[ln][f] = ai[oq];
                    sgh[ln][f] = ah[oq];
                }
            }
        }
        __syncthreads();
        {
            int ln = tx >> 4, lane = tx & 15;
            int n = n0 + ln;
            if (n < N) {
                #pragma unroll
                for (int q = 0; q < 4; ++q) {
                    int f = lane * 4 + q;
                    float r  = sigmoid_fast(sgi[ln][f]       + sgh[ln][f]);
                    float z  = sigmoid_fast(sgi[ln][64 + f]  + sgh[ln][64 + f]);
                    float nn = tanh_fast   (sgi[ln][128 + f] + r * sgh[ln][128 + f]);
                    out_h[(size_t)n * 64 + f] = (1.0f - z) * nn + z * shv[ln][f];
                }
            }
            if (tx < 48) {
                int n2 = n0 + tx / 3;
                int d3 = tx % 3;
                if (n2 < N) {
                    float c = (float)max(cnt[n2], 1);
                    float xv = x[(size_t)n2 * 3 + d3];
                    float xp = x_sum[(size_t)n2 * 3 + d3] / c;
                    out_xmod [(size_t)n2 * 3 + d3] = xp - floorf(xp);
                    out_xdiff[(size_t)n2 * 3 + d3] = xp - xv;
                }
            }
        }
        __syncthreads();
    }
}

// ---------------------------------------------------------------------------
extern "C" void kernel_launch(void* const* d_in, const int* in_sizes, int n_in,
                              void* d_out, int out_size, void* d_ws, size_t ws_size,
                              hipStream_t stream)
{
    const float* h    = (const float*)d_in[0];
    const float* x    = (const float*)d_in[1];
    const float* r_ij = (const float*)d_in[2];
    const float* e_ij = (const float*)d_in[3];
    const int*   src  = (const int*)d_in[4];
    const int*   dst  = (const int*)d_in[5];
    const float* W1   = (const float*)d_in[6];
    const float* b1   = (const float*)d_in[7];
    const float* W2   = (const float*)d_in[8];
    const float* b2   = (const float*)d_in[9];
    const float* P1   = (const float*)d_in[10];
    const float* pb1  = (const float*)d_in[11];
    const float* P2   = (const float*)d_in[12];
    const float* pb2  = (const float*)d_in[13];
    const float* W_ih = (const float*)d_in[14];
    const float* W_hh = (const float*)d_in[15];
    const float* b_ih = (const float*)d_in[16];
    const float* b_hh = (const float*)d_in[17];

    int N = in_sizes[0] / 64;
    int E = in_sizes[2];

    float* ws     = (float*)d_ws;
    float* H1a    = ws;                               // N*64 f
    float* H1b    = H1a + (size_t)N * 64;             // N*64 f
    float* m_sum  = H1b + (size_t)N * 64;             // N*64 f  (zeroed)
    float* x_sum  = m_sum + (size_t)N * 64;           // N*3  f  (zeroed)
    int*   hist   = (int*)(x_sum + (size_t)N * 3);    // N    i  (zeroed)
    int*   cursor = hist + N;                         // N    i
    int*   order  = cursor + N;                       // E    i
    int*   blksum = order + E;                        // ~64  i

    // zero m_sum + x_sum + hist (contiguous)
    hipMemsetAsync(m_sum, 0, ((size_t)N * 64 + (size_t)N * 3 + N) * sizeof(float), stream);

    // ---- sort edges by src (counting sort; intra-segment order arbitrary) ----
    hist_kernel<<<2048, 256, 0, stream>>>(src, hist, E);
    int B = (N + SCAN_CHUNK - 1) / SCAN_CHUNK;
    scanA_kernel<<<B, 256, 0, stream>>>(hist, blksum, N);
    scanB_kernel<<<1, 64, 0, stream>>>(blksum, B);
    scanC_kernel<<<B, 256, 0, stream>>>(hist, blksum, cursor, N);
    scatter_kernel<<<2048, 256, 0, stream>>>(src, cursor, order, E);

    // ---- node precompute ----
    node_pre_kernel<<<(N + 15) / 16, 256, 0, stream>>>(h, W1, b1, H1a, H1b, N);

    // ---- edge pipeline (m + x reductions fused) ----
    edge_kernel<<<2048, 256, 0, stream>>>(H1a, H1b, x, r_ij, e_ij, src, dst,
        order, W1, W2, b2, P1, pb1, P2, pb2, m_sum, x_sum, E);

    // ---- GRU + all outputs (persistent blocks) ----
    float* out_xmod  = (float*)d_out;
    float* out_xdiff = out_xmod + (size_t)N * 3;
    float* out_h     = out_xdiff + (size_t)N * 3;
    gru_kernel<<<256, 256, 0, stream>>>(h, x, m_sum, x_sum, hist,
        W_ih, W_hh, b_ih, b_hh, out_xmod, out_xdiff, out_h, N);
}

// Round 16
// 1840.165 us; speedup vs baseline: 1.4341x; 1.4341x over previous
//
#include <hip/hip_runtime.h>
#include <cstddef>

// ---------------------------------------------------------------------------
// EGNN layer, fp32. R16 = R14 verbatim (best validated: 1859us).
//   R15's per-tile weight restaging REVERTED: its sW[k][f] staging writes were
//   32-way bank-conflicted (lane stride 64 floats -> single bank), conflicts
//   6.1e7 -> 4.42e8, VGPR 84->124, occupancy fell -> edge 1163 -> 1994us.
//   Weights are staged once per block (amortized), as in R14.
// Pipeline: counting-sort by src -> node_pre (H1a/H1b) -> edge (2x tile-GEMM,
// segmented m/x reductions, few atomics) -> gru (LDS weights) + x finalize.
// ---------------------------------------------------------------------------

__device__ __forceinline__ float silu_f(float v) {
    return v * __builtin_amdgcn_rcpf(1.0f + __expf(-v));
}
__device__ __forceinline__ float sigmoid_fast(float v) {
    return __builtin_amdgcn_rcpf(1.0f + __expf(-v));
}
__device__ __forceinline__ float tanh_fast(float v) {
    return 2.0f * __builtin_amdgcn_rcpf(1.0f + __expf(-2.0f * v)) - 1.0f;
}

// ---------------- sort: histogram / scan / scatter ---------------------------
__global__ __launch_bounds__(256) void hist_kernel(
    const int* __restrict__ src, int* __restrict__ hist, int E)
{
    int i = blockIdx.x * 256 + threadIdx.x;
    int stride = gridDim.x * 256;
    for (; i < E; i += stride) atomicAdd(&hist[src[i]], 1);
}

#define SCAN_CHUNK 2048

__global__ __launch_bounds__(256) void scanA_kernel(
    const int* __restrict__ hist, int* __restrict__ blksum, int N)
{
    __shared__ int sred[256];
    int b = blockIdx.x, tx = threadIdx.x;
    int base = b * SCAN_CHUNK + tx * 8;
    int s = 0;
    #pragma unroll
    for (int i = 0; i < 8; ++i) { int idx = base + i; if (idx < N) s += hist[idx]; }
    sred[tx] = s; __syncthreads();
    for (int off = 128; off > 0; off >>= 1) {
        if (tx < off) sred[tx] += sred[tx + off];
        __syncthreads();
    }
    if (tx == 0) blksum[b] = sred[0];
}

__global__ void scanB_kernel(int* __restrict__ blksum, int B)
{
    if (blockIdx.x == 0 && threadIdx.x == 0) {
        int acc = 0;
        for (int i = 0; i < B; ++i) { int v = blksum[i]; blksum[i] = acc; acc += v; }
    }
}

__global__ __launch_bounds__(256) void scanC_kernel(
    const int* __restrict__ hist, const int* __restrict__ blksum,
    int* __restrict__ cursor, int N)
{
    __shared__ int sscan[256];
    int b = blockIdx.x, tx = threadIdx.x;
    int base = b * SCAN_CHUNK + tx * 8;
    int s = 0;
    #pragma unroll
    for (int i = 0; i < 8; ++i) { int idx = base + i; if (idx < N) s += hist[idx]; }
    int mysum = s;
    sscan[tx] = s; __syncthreads();
    for (int off = 1; off < 256; off <<= 1) {
        int v = (tx >= off) ? sscan[tx - off] : 0;
        __syncthreads();
        sscan[tx] += v;
        __syncthreads();
    }
    int run = blksum[b] + sscan[tx] - mysum;
    #pragma unroll
    for (int i = 0; i < 8; ++i) {
        int idx = base + i;
        if (idx < N) { cursor[idx] = run; run += hist[idx]; }
    }
}

__global__ __launch_bounds__(256) void scatter_kernel(
    const int* __restrict__ src, int* __restrict__ cursor,
    int* __restrict__ order, int E)
{
    int i = blockIdx.x * 256 + threadIdx.x;
    int stride = gridDim.x * 256;
    for (; i < E; i += stride) {
        int p = atomicAdd(&cursor[src[i]], 1);
        order[p] = i;
    }
}

// ---------------- K1: per-node precompute (LDS-staged W1^T, float4) ----------
__global__ __launch_bounds__(256) void node_pre_kernel(
    const float* __restrict__ h, const float* __restrict__ W1,
    const float* __restrict__ b1,
    float* __restrict__ H1a, float* __restrict__ H1b, int N)
{
    __shared__ float sh[16][68];
    __shared__ float sWT[64][132];
    __shared__ float sb1[64];
    int n0 = blockIdx.x * 16;
    int tx = threadIdx.x;
    for (int i = tx; i < 64 * 128; i += 256) {
        int o = i & 127, k = i >> 7;
        sWT[k][o] = (o < 64) ? W1[o * 129 + k] : W1[(o - 64) * 129 + 64 + k];
    }
    if (tx < 64) sb1[tx] = b1[tx];
    for (int i = tx; i < 16 * 64; i += 256) {
        int ln = i >> 6, k = i & 63;
        int n = n0 + ln;
        sh[ln][k] = (n < N) ? h[(size_t)n * 64 + k] : 0.0f;
    }
    __syncthreads();
    int ln = tx >> 4;
    int lane = tx & 15;
    int n = n0 + ln;
    if (n >= N) return;
    int o0 = lane * 8;
    float acc[8];
    #pragma unroll
    for (int q = 0; q < 8; ++q) acc[q] = (o0 < 64) ? sb1[o0 + q] : 0.0f;
    #pragma unroll 8
    for (int k = 0; k < 64; ++k) {
        float a = sh[ln][k];
        float4 w0 = *(const float4*)&sWT[k][o0];
        float4 w1 = *(const float4*)&sWT[k][o0 + 4];
        acc[0] += a * w0.x; acc[1] += a * w0.y; acc[2] += a * w0.z; acc[3] += a * w0.w;
        acc[4] += a * w1.x; acc[5] += a * w1.y; acc[6] += a * w1.z; acc[7] += a * w1.w;
    }
    if (o0 < 64) {
        *(float4*)(H1a + (size_t)n * 64 + o0)     = make_float4(acc[0], acc[1], acc[2], acc[3]);
        *(float4*)(H1a + (size_t)n * 64 + o0 + 4) = make_float4(acc[4], acc[5], acc[6], acc[7]);
    } else {
        int ob = o0 - 64;
        *(float4*)(H1b + (size_t)n * 64 + ob)     = make_float4(acc[0], acc[1], acc[2], acc[3]);
        *(float4*)(H1b + (size_t)n * 64 + ob + 4) = make_float4(acc[4], acc[5], acc[6], acc[7]);
    }
}

// ---------------- K2: edge pipeline on sorted order --------------------------
__device__ __forceinline__ void tile_gemm(
    const float (*__restrict__ Ain)[68],   // [k][e]
    const float (*__restrict__ WT)[64],    // [k][f]
    int te, int tf, float (&acc)[4][4])
{
    #pragma unroll
    for (int q = 0; q < 4; ++q)
        acc[q][0] = acc[q][1] = acc[q][2] = acc[q][3] = 0.0f;
    #pragma unroll
    for (int k = 0; k < 64; k += 4) {
        float4 av[4], wv[4];
        #pragma unroll
        for (int kk = 0; kk < 4; ++kk) av[kk] = *(const float4*)&Ain[k + kk][4 * te];
        #pragma unroll
        for (int kk = 0; kk < 4; ++kk) wv[kk] = *(const float4*)&WT[k + kk][4 * tf];
        #pragma unroll
        for (int kk = 0; kk < 4; ++kk) {
            float a0 = av[kk].x, a1 = av[kk].y, a2 = av[kk].z, a3 = av[kk].w;
            float w0 = wv[kk].x, w1 = wv[kk].y, w2 = wv[kk].z, w3 = wv[kk].w;
            acc[0][0] += a0 * w0; acc[0][1] += a0 * w1; acc[0][2] += a0 * w2; acc[0][3] += a0 * w3;
            acc[1][0] += a1 * w0; acc[1][1] += a1 * w1; acc[1][2] += a1 * w2; acc[1][3] += a1 * w3;
            acc[2][0] += a2 * w0; acc[2][1] += a2 * w1; acc[2][2] += a2 * w2; acc[2][3] += a2 * w3;
            acc[3][0] += a3 * w0; acc[3][1] += a3 * w1; acc[3][2] += a3 * w2; acc[3][3] += a3 * w3;
        }
    }
}

__global__ __launch_bounds__(256) void edge_kernel(
    const float* __restrict__ H1a, const float* __restrict__ H1b,
    const float* __restrict__ x,
    const float* __restrict__ r_ij, const float* __restrict__ e_ij,
    const int* __restrict__ src, const int* __restrict__ dst,
    const int* __restrict__ order,
    const float* __restrict__ W1, const float* __restrict__ W2,
    const float* __restrict__ b2, const float* __restrict__ P1,
    const float* __restrict__ pb1, const float* __restrict__ P2,
    const float* __restrict__ pb2,
    float* __restrict__ m_sum, float* __restrict__ x_sum, int E)
{
    __shared__ float sW2T[64][64];   // [k][f]
    __shared__ float sP1T[64][64];
    __shared__ float sA[64][68];     // [k][e] as t1, then [f][e] as m (in place)
    __shared__ float sXc[3][64];
    __shared__ int   sSrc[64];
    __shared__ int   sEid[64];
    __shared__ int   sRunStart[65];
    __shared__ int   sNRuns, sValid;
    __shared__ float sP2[64], sb2v[64], spb1[64], sW1c[64];
    __shared__ float spb2s;

    int tx = threadIdx.x;
    for (int i = tx; i < 64 * 64; i += 256) {
        int f = i >> 6, k = i & 63;
        sW2T[k][f] = W2[f * 64 + k];
        sP1T[k][f] = P1[f * 64 + k];
    }
    if (tx < 64) {
        sP2[tx]  = P2[tx];
        sb2v[tx] = b2[tx];
        spb1[tx] = pb1[tx];
        sW1c[tx] = W1[tx * 129 + 128];
    }
    if (tx == 0) spb2s = pb2[0];
    __syncthreads();

    int tf = tx & 15, te = tx >> 4;
    int ntile = (E + 63) >> 6;
    for (int t = blockIdx.x; t < ntile; t += gridDim.x) {
        int e0 = t << 6;

        // ---- phase 0: gather via sorted order + first layer -> sA[k][e]
        {
            int le = tx >> 2, j = tx & 3;
            int ep = e0 + le;
            bool ok = ep < E;
            int eid = ok ? order[ep] : 0;
            int s = src[eid], d = dst[eid];
            float r = r_ij[eid];
            if (j == 0) { sSrc[le] = ok ? s : -1; sEid[le] = eid; }
            const float* pa = H1a + (size_t)s * 64 + j * 16;
            const float* pb = H1b + (size_t)d * 64 + j * 16;
            #pragma unroll
            for (int q = 0; q < 4; ++q) {
                float4 va = *(const float4*)(pa + 4 * q);
                float4 vb = *(const float4*)(pb + 4 * q);
                int f = j * 16 + 4 * q;
                sA[f + 0][le] = silu_f(va.x + vb.x + r * sW1c[f + 0]);
                sA[f + 1][le] = silu_f(va.y + vb.y + r * sW1c[f + 1]);
                sA[f + 2][le] = silu_f(va.z + vb.z + r * sW1c[f + 2]);
                sA[f + 3][le] = silu_f(va.w + vb.w + r * sW1c[f + 3]);
            }
        }
        __syncthreads();                        // B1: sA(t1), sSrc, sEid ready

        // ---- run detection (wave 0; all ballots with full wave active) ----
        if (tx < 64) {
            int le = tx;
            int sv = sSrc[le];
            bool valid = sv >= 0;
            bool flag = valid && (le == 0 || sSrc[le - 1] != sv);
            unsigned long long vm = __ballot(valid);
            unsigned long long fm = __ballot(flag);
            if (flag) {
                int idx = __popcll(fm & ((1ull << le) - 1ull));
                sRunStart[idx] = le;
            }
            if (le == 0) {
                sNRuns = __popcll(fm);
                sValid = __popcll(vm);
            }
        }

        // ---- GEMM1: m = silu(t1@W2^T + b2), held in registers
        float m4v[4][4];
        {
            float acc[4][4];
            tile_gemm(sA, sW2T, te, tf, acc);
            #pragma unroll
            for (int c = 0; c < 4; ++c) {
                float b = sb2v[4 * tf + c];
                m4v[0][c] = silu_f(acc[0][c] + b);
                m4v[1][c] = silu_f(acc[1][c] + b);
                m4v[2][c] = silu_f(acc[2][c] + b);
                m4v[3][c] = silu_f(acc[3][c] + b);
            }
        }
        __syncthreads();                        // B2: all reads of sA(t1) done

        #pragma unroll
        for (int c = 0; c < 4; ++c) {
            float4 m4 = make_float4(m4v[0][c], m4v[1][c], m4v[2][c], m4v[3][c]);
            *(float4*)&sA[4 * tf + c][4 * te] = m4;
        }
        __syncthreads();                        // B3: sA(m) visible

        // ---- GEMM2: p = silu(m@P1^T+pb1); w = p.P2 + pb2 -> sXc = e_ij*w
        {
            float acc[4][4];
            tile_gemm(sA, sP1T, te, tf, acc);
            float w0 = 0.0f, w1 = 0.0f, w2 = 0.0f, w3 = 0.0f;
            #pragma unroll
            for (int c = 0; c < 4; ++c) {
                float p2 = sP2[4 * tf + c];
                float bb = spb1[4 * tf + c];
                w0 += silu_f(acc[0][c] + bb) * p2;
                w1 += silu_f(acc[1][c] + bb) * p2;
                w2 += silu_f(acc[2][c] + bb) * p2;
                w3 += silu_f(acc[3][c] + bb) * p2;
            }
            #pragma unroll
            for (int mask = 1; mask < 16; mask <<= 1) {
                w0 += __shfl_xor(w0, mask);
                w1 += __shfl_xor(w1, mask);
                w2 += __shfl_xor(w2, mask);
                w3 += __shfl_xor(w3, mask);
            }
            if (tf < 4) {
                int eloc = 4 * te + tf;
                int ep = e0 + eloc;
                if (ep < E) {
                    float w = ((tf == 0) ? w0 : (tf == 1) ? w1 : (tf == 2) ? w2 : w3) + spb2s;
                    int eid = sEid[eloc];
                    sXc[0][eloc] = e_ij[(size_t)eid * 3 + 0] * w;
                    sXc[1][eloc] = e_ij[(size_t)eid * 3 + 1] * w;
                    sXc[2][eloc] = e_ij[(size_t)eid * 3 + 2] * w;
                }
            }
        }

        // ---- m segmented reduction (reads sA(m)), bank-conflict-free layout
        {
            int l15 = tx & 15;
            int eslot = (tx >> 4) & 3;
            int sg = tx >> 6;
            int f = sg * 16 + l15;
            int nr = sNRuns, vc = sValid;
            for (int ridx = 0; ridx < nr; ++ridx) {
                int st = sRunStart[ridx];
                int en = (ridx + 1 < nr) ? sRunStart[ridx + 1] : vc;
                float s = 0.0f;
                for (int e = st + eslot; e < en; e += 4) s += sA[f][e];
                s += __shfl_xor(s, 16);
                s += __shfl_xor(s, 32);
                if (eslot == 0) {
                    int node = sSrc[st];
                    atomicAdd(&m_sum[(size_t)node * 64 + f], s);
                }
            }
        }
        __syncthreads();                        // B4: sXc ready

        // ---- x segmented reduction: one thread per run
        if (tx < sNRuns) {
            int nr = sNRuns;
            int st = sRunStart[tx];
            int en = (tx + 1 < nr) ? sRunStart[tx + 1] : sValid;
            int node = sSrc[st];
            float s0 = 0.0f, s1 = 0.0f, s2 = 0.0f;
            for (int e = st; e < en; ++e) {
                s0 += sXc[0][e]; s1 += sXc[1][e]; s2 += sXc[2][e];
            }
            float len = (float)(en - st);
            atomicAdd(&x_sum[(size_t)node * 3 + 0], s0 + len * x[(size_t)node * 3 + 0]);
            atomicAdd(&x_sum[(size_t)node * 3 + 1], s1 + len * x[(size_t)node * 3 + 1]);
            atomicAdd(&x_sum[(size_t)node * 3 + 2], s2 + len * x[(size_t)node * 3 + 2]);
        }
        __syncthreads();                        // Bend: before next tile's writes
    }
}

// ---------------- K3: GRU + x finalize (LDS weights, persistent) -------------
__global__ __launch_bounds__(256) void gru_kernel(
    const float* __restrict__ h, const float* __restrict__ x,
    const float* __restrict__ m_sum, const float* __restrict__ x_sum,
    const int* __restrict__ cnt,
    const float* __restrict__ W_ih, const float* __restrict__ W_hh,
    const float* __restrict__ b_ih, const float* __restrict__ b_hh,
    float* __restrict__ out_xmod, float* __restrict__ out_xdiff,
    float* __restrict__ out_h, int N)
{
    __shared__ float sWih[192][68];
    __shared__ float sWhh[192][68];
    __shared__ float smi[16][68];
    __shared__ float shv[16][68];
    __shared__ float sgi[16][196];
    __shared__ float sgh[16][196];

    int tx = threadIdx.x;
    for (int i = tx; i < 192 * 64; i += 256) {
        int f = i >> 6, k = i & 63;
        sWih[f][k] = W_ih[i];
        sWhh[f][k] = W_hh[i];
    }
    __syncthreads();

    int ntile = (N + 15) >> 4;
    for (int t = blockIdx.x; t < ntile; t += gridDim.x) {
        int n0 = t << 4;

        for (int i = tx; i < 16 * 64; i += 256) {
            int ln = i >> 6, f = i & 63;
            int n = n0 + ln;
            if (n < N) {
                float c = (float)max(cnt[n], 1);
                smi[ln][f] = m_sum[(size_t)n * 64 + f] / c;
                shv[ln][f] = h[(size_t)n * 64 + f];
            } else { smi[ln][f] = 0.0f; shv[ln][f] = 0.0f; }
        }
        __syncthreads();
        {
            int ln = tx >> 4, lane = tx & 15;
            int n = n0 + ln;
            if (n < N) {
                float ai[12], ah[12];
                #pragma unroll
                for (int oq = 0; oq < 12; ++oq) {
                    int f = oq * 16 + lane;
                    ai[oq] = b_ih[f];
                    ah[oq] = b_hh[f];
                }
                #pragma unroll 4
                for (int k4 = 0; k4 < 16; ++k4) {
                    float4 mi4 = *(const float4*)&smi[ln][4 * k4];
                    float4 hv4 = *(const float4*)&shv[ln][4 * k4];
                    #pragma unroll
                    for (int oq = 0; oq < 12; ++oq) {
                        int f = oq * 16 + lane;
                        float4 wiv = *(const float4*)&sWih[f][4 * k4];
                        float4 whv = *(const float4*)&sWhh[f][4 * k4];
                        ai[oq] += mi4.x * wiv.x + mi4.y * wiv.y + mi4.z * wiv.z + mi4.w * wiv.w;
                        ah[oq] += hv4.x * whv.x + hv4.y * whv.y + hv4.z * whv.z + hv4.w * whv.w;
                    }
                }
                #pragma unroll
                for (int oq = 0; oq < 12; ++oq) {
                    int f = oq * 16 + lane;
                    sgi[ln][f] = ai[oq];
                    sgh[ln][f] = ah[oq];
                }
            }
        }
        __syncthreads();
        {
            int ln = tx >> 4, lane = tx & 15;
            int n = n0 + ln;
            if (n < N) {
                #pragma unroll
                for (int q = 0; q < 4; ++q) {
                    int f = lane * 4 + q;
                    float r  = sigmoid_fast(sgi[ln][f]       + sgh[ln][f]);
                    float z  = sigmoid_fast(sgi[ln][64 + f]  + sgh[ln][64 + f]);
                    float nn = tanh_fast   (sgi[ln][128 + f] + r * sgh[ln][128 + f]);
                    out_h[(size_t)n * 64 + f] = (1.0f - z) * nn + z * shv[ln][f];
                }
            }
            if (tx < 48) {
                int n2 = n0 + tx / 3;
                int d3 = tx % 3;
                if (n2 < N) {
                    float c = (float)max(cnt[n2], 1);
                    float xv = x[(size_t)n2 * 3 + d3];
                    float xp = x_sum[(size_t)n2 * 3 + d3] / c;
                    out_xmod [(size_t)n2 * 3 + d3] = xp - floorf(xp);
                    out_xdiff[(size_t)n2 * 3 + d3] = xp - xv;
                }
            }
        }
        __syncthreads();
    }
}

// ---------------------------------------------------------------------------
extern "C" void kernel_launch(void* const* d_in, const int* in_sizes, int n_in,
                              void* d_out, int out_size, void* d_ws, size_t ws_size,
                              hipStream_t stream)
{
    const float* h    = (const float*)d_in[0];
    const float* x    = (const float*)d_in[1];
    const float* r_ij = (const float*)d_in[2];
    const float* e_ij = (const float*)d_in[3];
    const int*   src  = (const int*)d_in[4];
    const int*   dst  = (const int*)d_in[5];
    const float* W1   = (const float*)d_in[6];
    const float* b1   = (const float*)d_in[7];
    const float* W2   = (const float*)d_in[8];
    const float* b2   = (const float*)d_in[9];
    const float* P1   = (const float*)d_in[10];
    const float* pb1  = (const float*)d_in[11];
    const float* P2   = (const float*)d_in[12];
    const float* pb2  = (const float*)d_in[13];
    const float* W_ih = (const float*)d_in[14];
    const float* W_hh = (const float*)d_in[15];
    const float* b_ih = (const float*)d_in[16];
    const float* b_hh = (const float*)d_in[17];

    int N = in_sizes[0] / 64;
    int E = in_sizes[2];

    float* ws     = (float*)d_ws;
    float* H1a    = ws;                               // N*64 f
    float* H1b    = H1a + (size_t)N * 64;             // N*64 f
    float* m_sum  = H1b + (size_t)N * 64;             // N*64 f  (zeroed)
    float* x_sum  = m_sum + (size_t)N * 64;           // N*3  f  (zeroed)
    int*   hist   = (int*)(x_sum + (size_t)N * 3);    // N    i  (zeroed)
    int*   cursor = hist + N;                         // N    i
    int*   order  = cursor + N;                       // E    i
    int*   blksum = order + E;                        // ~64  i

    // zero m_sum + x_sum + hist (contiguous)
    hipMemsetAsync(m_sum, 0, ((size_t)N * 64 + (size_t)N * 3 + N) * sizeof(float), stream);

    // ---- sort edges by src (counting sort; intra-segment order arbitrary) ----
    hist_kernel<<<2048, 256, 0, stream>>>(src, hist, E);
    int B = (N + SCAN_CHUNK - 1) / SCAN_CHUNK;
    scanA_kernel<<<B, 256, 0, stream>>>(hist, blksum, N);
    scanB_kernel<<<1, 64, 0, stream>>>(blksum, B);
    scanC_kernel<<<B, 256, 0, stream>>>(hist, blksum, cursor, N);
    scatter_kernel<<<2048, 256, 0, stream>>>(src, cursor, order, E);

    // ---- node precompute ----
    node_pre_kernel<<<(N + 15) / 16, 256, 0, stream>>>(h, W1, b1, H1a, H1b, N);

    // ---- edge pipeline (m + x reductions fused) ----
    edge_kernel<<<2048, 256, 0, stream>>>(H1a, H1b, x, r_ij, e_ij, src, dst,
        order, W1, W2, b2, P1, pb1, P2, pb2, m_sum, x_sum, E);

    // ---- GRU + all outputs (persistent blocks) ----
    float* out_xmod  = (float*)d_out;
    float* out_xdiff = out_xmod + (size_t)N * 3;
    float* out_h     = out_xdiff + (size_t)N * 3;
    gru_kernel<<<256, 256, 0, stream>>>(h, x, m_sum, x_sum, hist,
        W_ih, W_hh, b_ih, b_hh, out_xmod, out_xdiff, out_h, N);
}